// Round 9
// baseline (402.616 us; speedup 1.0000x reference)
//
#include <hip/hip_runtime.h>
#include <math.h>

#define DI __device__ __forceinline__

typedef __attribute__((ext_vector_type(4))) float  f32x4;
typedef __attribute__((ext_vector_type(4))) short  s16x4;
typedef __attribute__((ext_vector_type(8))) short  s16x8;
typedef __attribute__((ext_vector_type(4))) float  ffrag;
typedef s16x8 bfrag;

constexpr int NT = 8192;   // B*S tokens
constexpr int D  = 4096;
constexpr int NE = 8;      // experts
constexpr int KE = 128;    // E * R
constexpr int KX = D + KE; // 4224 extended K

DI short f2bf(float f) {
  unsigned u = __builtin_bit_cast(unsigned, f);
  u += 0x7FFFu + ((u >> 16) & 1u);   // RNE
  return (short)(u >> 16);
}
DI float bf2f(short h) {
  unsigned u = ((unsigned)(unsigned short)h) << 16;
  return __builtin_bit_cast(float, u);
}

#define GLOAD16(gp, lp)                                                        \
  __builtin_amdgcn_global_load_lds(                                            \
      (const __attribute__((address_space(1))) void*)(gp),                     \
      (__attribute__((address_space(3))) void*)(lp), 16, 0, 0)

// ---------------------------------------------------------------- detect (standalone, R5 form)
// flag=0: fp32 inputs; flag=1: bf16-packed. fp32 N(0,1) dword exponent field
// is in [110,140] essentially always; bf16-packed dwords never.
__global__ void moe_k_detect(const unsigned* __restrict__ x, int* __restrict__ flag) {
  int l = threadIdx.x;
  int cnt = 0;
  for (int i = l; i < 2048; i += 64) {
    unsigned e = (x[i] >> 23) & 0xFFu;
    cnt += (e >= 110u && e <= 140u) ? 1 : 0;
  }
#pragma unroll
  for (int o = 32; o; o >>= 1) cnt += __shfl_xor(cnt, o);
  if (l == 0) flag[0] = (cnt > 1024) ? 0 : 1;
}

// ---------------------------------------------------------------- prep + xrouter (fused)
// blocks [0,8192):      Wb[d][0:4096] = bf16(base_W)
// blocks [8192,8208):   Wb[d][4096+j] = bf16(2 * lora_B[j][d])
// blocks [8208,8336):   Abt[j][d]     = bf16(lora_A[e][d][r])
// blocks [8336,8848):   x-convert + router, 4 waves x 4 tokens each
//   (4 tokens/wave amortizes the per-iter router_W vector loads 4x:
//    router cache traffic 1 GB -> 256 MB)
__global__ __launch_bounds__(256)
void moe_k_prep_xr(const void* __restrict__ wp, const void* __restrict__ lAp,
                   const void* __restrict__ lBp, const void* __restrict__ xp,
                   const void* __restrict__ rp, const int* __restrict__ flag,
                   short* __restrict__ Wb, short* __restrict__ Abt,
                   short* __restrict__ Xb, float* __restrict__ wdense) {
  const bool bf = flag[0] != 0;
  int b = blockIdx.x, t = threadIdx.x;
  if (b < 8192) {
    int tid = b * 256 + t;
    int row = tid >> 9;
    int col = (tid & 511) << 3;
    s16x8 o;
    if (!bf) {
      const float* Wf = (const float*)wp;
      f32x4 v0 = *(const f32x4*)&Wf[(size_t)row * 4096 + col];
      f32x4 v1 = *(const f32x4*)&Wf[(size_t)row * 4096 + col + 4];
      o[0] = f2bf(v0[0]); o[1] = f2bf(v0[1]); o[2] = f2bf(v0[2]); o[3] = f2bf(v0[3]);
      o[4] = f2bf(v1[0]); o[5] = f2bf(v1[1]); o[6] = f2bf(v1[2]); o[7] = f2bf(v1[3]);
    } else {
      o = *(const s16x8*)&((const short*)wp)[(size_t)row * 4096 + col];
    }
    *(s16x8*)&Wb[(size_t)row * KX + col] = o;
  } else if (b < 8208) {
    int d = (b - 8192) * 256 + t;
    for (int j0 = 0; j0 < KE; j0 += 8) {
      s16x8 o;
#pragma unroll
      for (int i = 0; i < 8; ++i) {
        float v = bf ? bf2f(((const short*)lBp)[(size_t)(j0 + i) * 4096 + d])
                     : ((const float*)lBp)[(size_t)(j0 + i) * 4096 + d];
        o[i] = f2bf(2.0f * v);
      }
      *(s16x8*)&Wb[(size_t)d * KX + 4096 + j0] = o;
    }
  } else if (b < 8336) {
    int j = b - 8208;
    int e = j >> 4, r = j & 15;
    for (int d = t; d < 4096; d += 256) {
      size_t src = ((size_t)e * 4096 + d) * 16 + r;
      short v = bf ? ((const short*)lAp)[src] : f2bf(((const float*)lAp)[src]);
      Abt[(size_t)j * 4096 + d] = v;
    }
  } else {
    // ---- xrouter: 4 tokens per wave
    int wv = t >> 6, l = t & 63;
    int n0 = (b - 8336) * 16 + wv * 4;
    float acc[4][NE];
#pragma unroll
    for (int k = 0; k < 4; ++k)
#pragma unroll
      for (int e = 0; e < NE; ++e) acc[k][e] = 0.f;
    const float* xf = (const float*)xp;
    const short* xh = (const short*)xp;
    const float* rf = (const float*)rp;
    const short* rh = (const short*)rp;
    for (int it = 0; it < 16; ++it) {
      int d = it * 256 + l * 4;
      // router vectors for this d-slice, loaded ONCE for all 4 tokens
      f32x4 rv[NE];
#pragma unroll
      for (int e = 0; e < NE; ++e) {
        if (!bf) {
          rv[e] = *(const f32x4*)&rf[(size_t)e * D + d];
        } else {
          s16x4 w = *(const s16x4*)&rh[(size_t)e * D + d];
          f32x4 v;
          v[0] = bf2f(w[0]); v[1] = bf2f(w[1]); v[2] = bf2f(w[2]); v[3] = bf2f(w[3]);
          rv[e] = v;
        }
      }
#pragma unroll
      for (int k = 0; k < 4; ++k) {
        int n = n0 + k;
        float x0, x1, x2, x3;
        s16x4 xo;
        if (!bf) {
          f32x4 v = *(const f32x4*)&xf[(size_t)n * D + d];
          x0 = v[0]; x1 = v[1]; x2 = v[2]; x3 = v[3];
          xo[0] = f2bf(x0); xo[1] = f2bf(x1); xo[2] = f2bf(x2); xo[3] = f2bf(x3);
        } else {
          xo = *(const s16x4*)&xh[(size_t)n * D + d];
          x0 = bf2f(xo[0]); x1 = bf2f(xo[1]); x2 = bf2f(xo[2]); x3 = bf2f(xo[3]);
        }
        *(s16x4*)&Xb[(size_t)n * KX + d] = xo;
#pragma unroll
        for (int e = 0; e < NE; ++e)
          acc[k][e] += x0 * rv[e][0] + x1 * rv[e][1] + x2 * rv[e][2] + x3 * rv[e][3];
      }
    }
#pragma unroll
    for (int k = 0; k < 4; ++k) {
#pragma unroll
      for (int e = 0; e < NE; ++e) {
#pragma unroll
        for (int o = 32; o; o >>= 1) acc[k][e] += __shfl_xor(acc[k][e], o);
      }
      float m = acc[k][0];
#pragma unroll
      for (int e = 1; e < NE; ++e) m = fmaxf(m, acc[k][e]);
      float p[NE];
#pragma unroll
      for (int e = 0; e < NE; ++e) p[e] = __expf(acc[k][e] - m);
      int i1 = 0; float v1 = p[0];
#pragma unroll
      for (int e = 1; e < NE; ++e) { if (p[e] > v1) { v1 = p[e]; i1 = e; } }
      int i2 = 0; float v2 = -1.f;
#pragma unroll
      for (int e = 0; e < NE; ++e) { if (e != i1 && p[e] > v2) { v2 = p[e]; i2 = e; } }
      float inv = 1.f / (v1 + v2);
      if (l < NE) {
        float w = (l == i1) ? v1 * inv : ((l == i2) ? v2 * inv : 0.f);
        wdense[(size_t)(n0 + k) * NE + l] = w;
      }
    }
  }
}

// ---------------------------------------------------------------- mid GEMM v2 (R5 verbatim)
__global__ __launch_bounds__(256)
void moe_k_mid2(const short* __restrict__ Xb, const short* __restrict__ Abt,
                const float* __restrict__ wdense, short* __restrict__ XbW) {
  __shared__ __align__(16) short LDS[16384];
  const int t = threadIdx.x, l = t & 63, wv = t >> 6;
  const int wr = wv >> 1, wc = wv & 1;
  const int lr = l & 15, kq = l >> 4;
  const int m0 = (blockIdx.x >> 1) * 64;
  const int j0 = (blockIdx.x & 1) * 64;

  ffrag acc[2][2];
#pragma unroll
  for (int i = 0; i < 2; ++i)
#pragma unroll
    for (int j = 0; j < 2; ++j)
#pragma unroll
      for (int q = 0; q < 4; ++q) acc[i][j][q] = 0.f;

  const int srow = t >> 2, sslot = t & 3;
#define MSTAGE(kt_)                                                            \
  do {                                                                         \
    int _k0 = (kt_) * 32, _b = ((kt_) & 3) * 4096;                             \
    GLOAD16(&Xb[(size_t)(m0 + srow) * KX + _k0 + sslot * 8], &LDS[_b + t * 8]);\
    GLOAD16(&Abt[(size_t)(j0 + srow) * 4096 + _k0 + sslot * 8],                \
            &LDS[_b + 2048 + t * 8]);                                          \
  } while (0)

  MSTAGE(0); MSTAGE(1); MSTAGE(2);
  constexpr int NKT = 128;

  for (int kt = 0; kt < NKT; ++kt) {
    if (kt + 2 < NKT)      asm volatile("s_waitcnt vmcnt(4)" ::: "memory");
    else if (kt + 1 < NKT) asm volatile("s_waitcnt vmcnt(2)" ::: "memory");
    else                   asm volatile("s_waitcnt vmcnt(0)" ::: "memory");
    __builtin_amdgcn_s_barrier();
    __builtin_amdgcn_sched_barrier(0);

    const int bufs = (kt & 3) * 4096;
    const short* As = &LDS[bufs + (wr * 32 + lr) * 32 + kq * 8];
    const short* Bs = &LDS[bufs + 2048 + (wc * 32 + lr) * 32 + kq * 8];
    bfrag a0 = *(const bfrag*)&As[0];
    bfrag a1 = *(const bfrag*)&As[512];
    bfrag b0 = *(const bfrag*)&Bs[0];
    bfrag b1 = *(const bfrag*)&Bs[512];
    if (kt + 3 < NKT) MSTAGE(kt + 3);
    asm volatile("" ::: "memory");
    acc[0][0] = __builtin_amdgcn_mfma_f32_16x16x32_bf16(b0, a0, acc[0][0], 0, 0, 0);
    acc[0][1] = __builtin_amdgcn_mfma_f32_16x16x32_bf16(b1, a0, acc[0][1], 0, 0, 0);
    acc[1][0] = __builtin_amdgcn_mfma_f32_16x16x32_bf16(b0, a1, acc[1][0], 0, 0, 0);
    acc[1][1] = __builtin_amdgcn_mfma_f32_16x16x32_bf16(b1, a1, acc[1][1], 0, 0, 0);
  }

#pragma unroll
  for (int m = 0; m < 2; ++m)
#pragma unroll
    for (int n = 0; n < 2; ++n) {
      int gr = m0 + wr * 32 + m * 16 + lr;
      int jb = j0 + wc * 32 + n * 16 + kq * 4;
      int e  = jb >> 4;
      float w = wdense[(size_t)gr * NE + e];
      s16x4 o;
#pragma unroll
      for (int q = 0; q < 4; ++q) o[q] = f2bf(acc[m][n][q] * w);
      *(s16x4*)&XbW[(size_t)gr * KX + 4096 + jb] = o;
    }
#undef MSTAGE
}

// ---------------------------------------------------------------- main GEMM (R5 verbatim — best measured: 249 us, 0 conflicts)
__global__ __launch_bounds__(512, 2)
void moe_k_main8(const short* __restrict__ Xb, const short* __restrict__ Wb,
                 const int* __restrict__ flag, void* __restrict__ outp) {
  __shared__ __align__(16) short LDS[65536];  // 128 KiB: ring-4 x (A 16KB + B 16KB)
  const int t = threadIdx.x;
  const int l = t & 63;
  const int wv = t >> 6;
  const int wr = wv >> 2;
  const int wc = wv & 3;
  const int lr = l & 15;
  const int kq = l >> 4;

  int wg = blockIdx.x;
  int swz = (wg & 7) * 64 + (wg >> 3);
  const int tm = (swz >> 4) * 256;
  const int tn = (swz & 15) * 256;

  ffrag acc[8][4];
#pragma unroll
  for (int i = 0; i < 8; ++i)
#pragma unroll
    for (int j = 0; j < 4; ++j)
#pragma unroll
      for (int q = 0; q < 4; ++q) acc[i][j][q] = 0.f;

#define STAGE_A(kt_)                                                           \
  do {                                                                         \
    int _k0 = (kt_) * 32, _b = ((kt_) & 3) * 16384;                            \
    _Pragma("unroll")                                                          \
    for (int _i = 0; _i < 2; ++_i) {                                           \
      int _c = _i * 512 + t;                                                   \
      int _r = _c >> 2;                                                        \
      int _kc = (_c & 3) ^ ((_r >> 1) & 3);                                    \
      GLOAD16(&Xb[(size_t)(tm + _r) * KX + _k0 + _kc * 8], &LDS[_b + _c * 8]); \
    }                                                                          \
  } while (0)
#define STAGE_B(kt_)                                                           \
  do {                                                                         \
    int _k0 = (kt_) * 32, _b = ((kt_) & 3) * 16384 + 8192;                     \
    _Pragma("unroll")                                                          \
    for (int _i = 0; _i < 2; ++_i) {                                           \
      int _c = _i * 512 + t;                                                   \
      int _r = _c >> 2;                                                        \
      int _kc = (_c & 3) ^ ((_r >> 1) & 3);                                    \
      GLOAD16(&Wb[(size_t)(tn + _r) * KX + _k0 + _kc * 8], &LDS[_b + _c * 8]); \
    }                                                                          \
  } while (0)

  STAGE_A(0); STAGE_B(0);
  STAGE_A(1); STAGE_B(1);
  STAGE_A(2); STAGE_B(2);

  constexpr int NKT = KX / 32;  // 132

  const int kx = kq ^ ((lr >> 1) & 3);
  const int aofs = (wr * 128 + lr) * 32 + kx * 8;
  const int bofs = 8192 + (wc * 64 + lr) * 32 + kx * 8;

  // frag sets: C = current tile, N = next tile (ping-pong via x2 unroll)
  bfrag bA[4], aA[8], bB[4], aB[8];

  // prologue: tiles 0,1 resident after vmcnt(4); load tile-0 phase-A frags
  asm volatile("s_waitcnt vmcnt(4)" ::: "memory");
  __builtin_amdgcn_s_barrier();
  asm volatile("" ::: "memory");
  {
    const short* Ab0 = &LDS[aofs];
    const short* Bb0 = &LDS[bofs];
#pragma unroll
    for (int i = 0; i < 4; ++i) bA[i] = *(const bfrag*)&Bb0[i * 512];
#pragma unroll
    for (int i = 0; i < 4; ++i) aA[i] = *(const bfrag*)&Ab0[i * 512];
  }

  // one tile: CURB/CURA consumed; NXTB/NXTA loaded (unless LAST)
#define TILE_BODY(kt_, CURB, CURA, NXTB, NXTA, LAST)                           \
  {                                                                            \
    const int _slc = ((kt_) & 3) * 16384;                                      \
    const short* _AbC = &LDS[_slc + aofs];                                     \
    _Pragma("unroll")                                                          \
    for (int _i = 0; _i < 4; ++_i)                                             \
      CURA[4 + _i] = *(const bfrag*)&_AbC[2048 + _i * 512];                    \
    if ((kt_) + 3 < NKT) STAGE_A((kt_) + 3);                                   \
    __builtin_amdgcn_sched_barrier(0);                                         \
    __builtin_amdgcn_s_setprio(1);                                             \
    _Pragma("unroll")                                                          \
    for (int _m = 0; _m < 4; ++_m)                                             \
      _Pragma("unroll")                                                        \
      for (int _n = 0; _n < 4; ++_n)                                           \
        acc[_m][_n] = __builtin_amdgcn_mfma_f32_16x16x32_bf16(                 \
            CURB[_n], CURA[_m], acc[_m][_n], 0, 0, 0);                         \
    __builtin_amdgcn_s_setprio(0);                                             \
    if (!(LAST)) {                                                             \
      const int _sln = (((kt_) + 1) & 3) * 16384;                              \
      const short* _AbN = &LDS[_sln + aofs];                                   \
      const short* _BbN = &LDS[_sln + bofs];                                   \
      _Pragma("unroll")                                                        \
      for (int _i = 0; _i < 4; ++_i) NXTB[_i] = *(const bfrag*)&_BbN[_i * 512];\
      _Pragma("unroll")                                                        \
      for (int _i = 0; _i < 4; ++_i) NXTA[_i] = *(const bfrag*)&_AbN[_i * 512];\
    }                                                                          \
    if ((kt_) + 3 < NKT) STAGE_B((kt_) + 3);                                   \
    __builtin_amdgcn_sched_barrier(0);                                         \
    __builtin_amdgcn_s_setprio(1);                                             \
    _Pragma("unroll")                                                          \
    for (int _m = 4; _m < 8; ++_m)                                             \
      _Pragma("unroll")                                                        \
      for (int _n = 0; _n < 4; ++_n)                                           \
        acc[_m][_n] = __builtin_amdgcn_mfma_f32_16x16x32_bf16(                 \
            CURB[_n], CURA[_m], acc[_m][_n], 0, 0, 0);                         \
    __builtin_amdgcn_s_setprio(0);                                             \
    if (!(LAST)) {                                                             \
      if ((kt_) + 4 < NKT) { asm volatile("s_waitcnt vmcnt(4)" ::: "memory"); }\
      else                 { asm volatile("s_waitcnt vmcnt(0)" ::: "memory"); }\
      __builtin_amdgcn_s_barrier();                                            \
      asm volatile("" ::: "memory");                                          \
    }                                                                          \
  }

  for (int kt = 0; kt < NKT; kt += 2) {
    TILE_BODY(kt,     bA, aA, bB, aB, false);
    TILE_BODY(kt + 1, bB, aB, bA, aA, (kt + 2 >= NKT));
  }

  const bool bf = flag[0] != 0;
  float* of = (float*)outp;
  unsigned short* oh = (unsigned short*)outp;
#pragma unroll
  for (int m = 0; m < 8; ++m)
#pragma unroll
    for (int n = 0; n < 4; ++n) {
      int gr = tm + wr * 128 + m * 16 + lr;
      int gc = tn + wc * 64 + n * 16 + kq * 4;
      if (!bf) {
        *(f32x4*)&of[(size_t)gr * D + gc] = acc[m][n];
      } else {
        s16x4 o;
#pragma unroll
        for (int q = 0; q < 4; ++q) o[q] = f2bf(acc[m][n][q]);
        *(s16x4*)&oh[(size_t)gr * D + gc] = o;
      }
    }
#undef STAGE_A
#undef STAGE_B
#undef TILE_BODY
}

// ---------------------------------------------------------------- host
extern "C" void kernel_launch(void* const* d_in, const int* in_sizes, int n_in,
                              void* d_out, int out_size, void* d_ws, size_t ws_size,
                              hipStream_t stream) {
  const void* x  = d_in[0];
  const void* bw = d_in[1];
  const void* rw = d_in[2];
  const void* lA = d_in[3];
  const void* lB = d_in[4];

  char* ws = (char*)d_ws;
  const size_t XB_BYTES  = (size_t)NT * KX * 2;
  const size_t WB_BYTES  = (size_t)D * KX * 2;
  const size_t ABT_BYTES = (size_t)KE * D * 2;
  const size_t WD_BYTES  = (size_t)NT * NE * 4;
  const size_t NEED = 256 + XB_BYTES + WB_BYTES + ABT_BYTES + WD_BYTES;
  if (ws_size < NEED) return;

  int*   flag   = (int*)ws;
  short* Xb     = (short*)(ws + 256);
  short* Wb     = (short*)(ws + 256 + XB_BYTES);
  short* Abt    = (short*)(ws + 256 + XB_BYTES + WB_BYTES);
  float* wdense = (float*)(ws + 256 + XB_BYTES + WB_BYTES + ABT_BYTES);

  hipLaunchKernelGGL(moe_k_detect, dim3(1), dim3(64), 0, stream,
                     (const unsigned*)x, flag);
  hipLaunchKernelGGL(moe_k_prep_xr, dim3(8848), dim3(256), 0, stream,
                     bw, lA, lB, x, rw, flag, Wb, Abt, Xb, wdense);
  hipLaunchKernelGGL(moe_k_mid2, dim3(256), dim3(256), 0, stream,
                     Xb, Abt, wdense, Xb);
  hipLaunchKernelGGL(moe_k_main8, dim3(512), dim3(512), 0, stream,
                     Xb, Wb, flag, d_out);
}

// Round 10
// 394.545 us; speedup vs baseline: 1.0205x; 1.0205x over previous
//
#include <hip/hip_runtime.h>
#include <math.h>

#define DI __device__ __forceinline__

typedef __attribute__((ext_vector_type(4))) float  f32x4;
typedef __attribute__((ext_vector_type(4))) short  s16x4;
typedef __attribute__((ext_vector_type(8))) short  s16x8;
typedef __attribute__((ext_vector_type(4))) float  ffrag;
typedef s16x8 bfrag;

constexpr int NT = 8192;   // B*S tokens
constexpr int D  = 4096;
constexpr int NE = 8;      // experts
constexpr int KE = 128;    // E * R
constexpr int KX = D + KE; // 4224 extended K

DI short f2bf(float f) {
  unsigned u = __builtin_bit_cast(unsigned, f);
  u += 0x7FFFu + ((u >> 16) & 1u);   // RNE
  return (short)(u >> 16);
}
DI float bf2f(short h) {
  unsigned u = ((unsigned)(unsigned short)h) << 16;
  return __builtin_bit_cast(float, u);
}

#define GLOAD16(gp, lp)                                                        \
  __builtin_amdgcn_global_load_lds(                                            \
      (const __attribute__((address_space(1))) void*)(gp),                     \
      (__attribute__((address_space(3))) void*)(lp), 16, 0, 0)

// ---------------------------------------------------------------- detect (standalone)
__global__ void moe_k_detect(const unsigned* __restrict__ x, int* __restrict__ flag) {
  int l = threadIdx.x;
  int cnt = 0;
  for (int i = l; i < 2048; i += 64) {
    unsigned e = (x[i] >> 23) & 0xFFu;
    cnt += (e >= 110u && e <= 140u) ? 1 : 0;
  }
#pragma unroll
  for (int o = 32; o; o >>= 1) cnt += __shfl_xor(cnt, o);
  if (l == 0) flag[0] = (cnt > 1024) ? 0 : 1;
}

// ---------------------------------------------------------------- prep (streaming only, low VGPR)
// blocks [0,8192):      Wb[d][0:4096] = bf16(base_W)
// blocks [8192,8208):   Wb[d][4096+j] = bf16(2 * lora_B[j][d])
// blocks [8208,8336):   Abt[j][d]     = bf16(lora_A[e][d][r])
__global__ __launch_bounds__(256)
void moe_k_prep(const void* __restrict__ wp, const void* __restrict__ lAp,
                const void* __restrict__ lBp, const int* __restrict__ flag,
                short* __restrict__ Wb, short* __restrict__ Abt) {
  const bool bf = flag[0] != 0;
  int b = blockIdx.x, t = threadIdx.x;
  if (b < 8192) {
    int tid = b * 256 + t;
    int row = tid >> 9;
    int col = (tid & 511) << 3;
    s16x8 o;
    if (!bf) {
      const float* Wf = (const float*)wp;
      f32x4 v0 = *(const f32x4*)&Wf[(size_t)row * 4096 + col];
      f32x4 v1 = *(const f32x4*)&Wf[(size_t)row * 4096 + col + 4];
      o[0] = f2bf(v0[0]); o[1] = f2bf(v0[1]); o[2] = f2bf(v0[2]); o[3] = f2bf(v0[3]);
      o[4] = f2bf(v1[0]); o[5] = f2bf(v1[1]); o[6] = f2bf(v1[2]); o[7] = f2bf(v1[3]);
    } else {
      o = *(const s16x8*)&((const short*)wp)[(size_t)row * 4096 + col];
    }
    *(s16x8*)&Wb[(size_t)row * KX + col] = o;
  } else if (b < 8208) {
    int d = (b - 8192) * 256 + t;
    for (int j0 = 0; j0 < KE; j0 += 8) {
      s16x8 o;
#pragma unroll
      for (int i = 0; i < 8; ++i) {
        float v = bf ? bf2f(((const short*)lBp)[(size_t)(j0 + i) * 4096 + d])
                     : ((const float*)lBp)[(size_t)(j0 + i) * 4096 + d];
        o[i] = f2bf(2.0f * v);
      }
      *(s16x8*)&Wb[(size_t)d * KX + 4096 + j0] = o;
    }
  } else {
    int j = b - 8208;
    int e = j >> 4, r = j & 15;
    for (int d = t; d < 4096; d += 256) {
      size_t src = ((size_t)e * 4096 + d) * 16 + r;
      short v = bf ? ((const short*)lAp)[src] : f2bf(((const float*)lAp)[src]);
      Abt[(size_t)j * 4096 + d] = v;
    }
  }
}

// ---------------------------------------------------------------- xrouter (standalone, R5 logic)
// 2048 blocks x 4 waves, one token per wave: convert x row -> Xb[:,0:4096],
// fp32 router logits, softmax, top-2, normalized weights -> wdense.
__global__ __launch_bounds__(256)
void moe_k_xrouter(const void* __restrict__ xp, const void* __restrict__ rp,
                   const int* __restrict__ flag, short* __restrict__ Xb,
                   float* __restrict__ wdense) {
  const bool bf = flag[0] != 0;
  int t = threadIdx.x, wv = t >> 6, l = t & 63;
  int n = blockIdx.x * 4 + wv;
  float acc[NE];
#pragma unroll
  for (int e = 0; e < NE; ++e) acc[e] = 0.f;
  const float* xf = (const float*)xp;
  const short* xh = (const short*)xp;
  const float* rf = (const float*)rp;
  const short* rh = (const short*)rp;
  for (int it = 0; it < 16; ++it) {
    int d = it * 256 + l * 4;
    float x0, x1, x2, x3;
    s16x4 xo;
    if (!bf) {
      f32x4 v = *(const f32x4*)&xf[(size_t)n * D + d];
      x0 = v[0]; x1 = v[1]; x2 = v[2]; x3 = v[3];
      xo[0] = f2bf(x0); xo[1] = f2bf(x1); xo[2] = f2bf(x2); xo[3] = f2bf(x3);
    } else {
      xo = *(const s16x4*)&xh[(size_t)n * D + d];
      x0 = bf2f(xo[0]); x1 = bf2f(xo[1]); x2 = bf2f(xo[2]); x3 = bf2f(xo[3]);
    }
    *(s16x4*)&Xb[(size_t)n * KX + d] = xo;
#pragma unroll
    for (int e = 0; e < NE; ++e) {
      if (!bf) {
        f32x4 w = *(const f32x4*)&rf[(size_t)e * D + d];
        acc[e] += x0 * w[0] + x1 * w[1] + x2 * w[2] + x3 * w[3];
      } else {
        s16x4 w = *(const s16x4*)&rh[(size_t)e * D + d];
        acc[e] += x0 * bf2f(w[0]) + x1 * bf2f(w[1]) + x2 * bf2f(w[2]) + x3 * bf2f(w[3]);
      }
    }
  }
#pragma unroll
  for (int e = 0; e < NE; ++e) {
#pragma unroll
    for (int o = 32; o; o >>= 1) acc[e] += __shfl_xor(acc[e], o);
  }
  float m = acc[0];
#pragma unroll
  for (int e = 1; e < NE; ++e) m = fmaxf(m, acc[e]);
  float p[NE];
#pragma unroll
  for (int e = 0; e < NE; ++e) p[e] = __expf(acc[e] - m);
  int i1 = 0; float v1 = p[0];
#pragma unroll
  for (int e = 1; e < NE; ++e) { if (p[e] > v1) { v1 = p[e]; i1 = e; } }
  int i2 = 0; float v2 = -1.f;
#pragma unroll
  for (int e = 0; e < NE; ++e) { if (e != i1 && p[e] > v2) { v2 = p[e]; i2 = e; } }
  float inv = 1.f / (v1 + v2);
  if (l < NE) {
    float w = (l == i1) ? v1 * inv : ((l == i2) ? v2 * inv : 0.f);
    wdense[(size_t)n * NE + l] = w;
  }
}

// ---------------------------------------------------------------- mid GEMM v2 (R5 verbatim)
__global__ __launch_bounds__(256)
void moe_k_mid2(const short* __restrict__ Xb, const short* __restrict__ Abt,
                const float* __restrict__ wdense, short* __restrict__ XbW) {
  __shared__ __align__(16) short LDS[16384];
  const int t = threadIdx.x, l = t & 63, wv = t >> 6;
  const int wr = wv >> 1, wc = wv & 1;
  const int lr = l & 15, kq = l >> 4;
  const int m0 = (blockIdx.x >> 1) * 64;
  const int j0 = (blockIdx.x & 1) * 64;

  ffrag acc[2][2];
#pragma unroll
  for (int i = 0; i < 2; ++i)
#pragma unroll
    for (int j = 0; j < 2; ++j)
#pragma unroll
      for (int q = 0; q < 4; ++q) acc[i][j][q] = 0.f;

  const int srow = t >> 2, sslot = t & 3;
#define MSTAGE(kt_)                                                            \
  do {                                                                         \
    int _k0 = (kt_) * 32, _b = ((kt_) & 3) * 4096;                             \
    GLOAD16(&Xb[(size_t)(m0 + srow) * KX + _k0 + sslot * 8], &LDS[_b + t * 8]);\
    GLOAD16(&Abt[(size_t)(j0 + srow) * 4096 + _k0 + sslot * 8],                \
            &LDS[_b + 2048 + t * 8]);                                          \
  } while (0)

  MSTAGE(0); MSTAGE(1); MSTAGE(2);
  constexpr int NKT = 128;

  for (int kt = 0; kt < NKT; ++kt) {
    if (kt + 2 < NKT)      asm volatile("s_waitcnt vmcnt(4)" ::: "memory");
    else if (kt + 1 < NKT) asm volatile("s_waitcnt vmcnt(2)" ::: "memory");
    else                   asm volatile("s_waitcnt vmcnt(0)" ::: "memory");
    __builtin_amdgcn_s_barrier();
    __builtin_amdgcn_sched_barrier(0);

    const int bufs = (kt & 3) * 4096;
    const short* As = &LDS[bufs + (wr * 32 + lr) * 32 + kq * 8];
    const short* Bs = &LDS[bufs + 2048 + (wc * 32 + lr) * 32 + kq * 8];
    bfrag a0 = *(const bfrag*)&As[0];
    bfrag a1 = *(const bfrag*)&As[512];
    bfrag b0 = *(const bfrag*)&Bs[0];
    bfrag b1 = *(const bfrag*)&Bs[512];
    if (kt + 3 < NKT) MSTAGE(kt + 3);
    asm volatile("" ::: "memory");
    acc[0][0] = __builtin_amdgcn_mfma_f32_16x16x32_bf16(b0, a0, acc[0][0], 0, 0, 0);
    acc[0][1] = __builtin_amdgcn_mfma_f32_16x16x32_bf16(b1, a0, acc[0][1], 0, 0, 0);
    acc[1][0] = __builtin_amdgcn_mfma_f32_16x16x32_bf16(b0, a1, acc[1][0], 0, 0, 0);
    acc[1][1] = __builtin_amdgcn_mfma_f32_16x16x32_bf16(b1, a1, acc[1][1], 0, 0, 0);
  }

#pragma unroll
  for (int m = 0; m < 2; ++m)
#pragma unroll
    for (int n = 0; n < 2; ++n) {
      int gr = m0 + wr * 32 + m * 16 + lr;
      int jb = j0 + wc * 32 + n * 16 + kq * 4;
      int e  = jb >> 4;
      float w = wdense[(size_t)gr * NE + e];
      s16x4 o;
#pragma unroll
      for (int q = 0; q < 4; ++q) o[q] = f2bf(acc[m][n][q] * w);
      *(s16x4*)&XbW[(size_t)gr * KX + 4096 + jb] = o;
    }
#undef MSTAGE
}

// ---------------------------------------------------------------- main GEMM (R5 verbatim — best measured: 249 us, 0 conflicts)
__global__ __launch_bounds__(512, 2)
void moe_k_main8(const short* __restrict__ Xb, const short* __restrict__ Wb,
                 const int* __restrict__ flag, void* __restrict__ outp) {
  __shared__ __align__(16) short LDS[65536];  // 128 KiB: ring-4 x (A 16KB + B 16KB)
  const int t = threadIdx.x;
  const int l = t & 63;
  const int wv = t >> 6;
  const int wr = wv >> 2;
  const int wc = wv & 3;
  const int lr = l & 15;
  const int kq = l >> 4;

  int wg = blockIdx.x;
  int swz = (wg & 7) * 64 + (wg >> 3);
  const int tm = (swz >> 4) * 256;
  const int tn = (swz & 15) * 256;

  ffrag acc[8][4];
#pragma unroll
  for (int i = 0; i < 8; ++i)
#pragma unroll
    for (int j = 0; j < 4; ++j)
#pragma unroll
      for (int q = 0; q < 4; ++q) acc[i][j][q] = 0.f;

#define STAGE_A(kt_)                                                           \
  do {                                                                         \
    int _k0 = (kt_) * 32, _b = ((kt_) & 3) * 16384;                            \
    _Pragma("unroll")                                                          \
    for (int _i = 0; _i < 2; ++_i) {                                           \
      int _c = _i * 512 + t;                                                   \
      int _r = _c >> 2;                                                        \
      int _kc = (_c & 3) ^ ((_r >> 1) & 3);                                    \
      GLOAD16(&Xb[(size_t)(tm + _r) * KX + _k0 + _kc * 8], &LDS[_b + _c * 8]); \
    }                                                                          \
  } while (0)
#define STAGE_B(kt_)                                                           \
  do {                                                                         \
    int _k0 = (kt_) * 32, _b = ((kt_) & 3) * 16384 + 8192;                     \
    _Pragma("unroll")                                                          \
    for (int _i = 0; _i < 2; ++_i) {                                           \
      int _c = _i * 512 + t;                                                   \
      int _r = _c >> 2;                                                        \
      int _kc = (_c & 3) ^ ((_r >> 1) & 3);                                    \
      GLOAD16(&Wb[(size_t)(tn + _r) * KX + _k0 + _kc * 8], &LDS[_b + _c * 8]); \
    }                                                                          \
  } while (0)

  STAGE_A(0); STAGE_B(0);
  STAGE_A(1); STAGE_B(1);
  STAGE_A(2); STAGE_B(2);

  constexpr int NKT = KX / 32;  // 132

  const int kx = kq ^ ((lr >> 1) & 3);
  const int aofs = (wr * 128 + lr) * 32 + kx * 8;
  const int bofs = 8192 + (wc * 64 + lr) * 32 + kx * 8;

  // frag sets: C = current tile, N = next tile (ping-pong via x2 unroll)
  bfrag bA[4], aA[8], bB[4], aB[8];

  // prologue: tiles 0,1 resident after vmcnt(4); load tile-0 phase-A frags
  asm volatile("s_waitcnt vmcnt(4)" ::: "memory");
  __builtin_amdgcn_s_barrier();
  asm volatile("" ::: "memory");
  {
    const short* Ab0 = &LDS[aofs];
    const short* Bb0 = &LDS[bofs];
#pragma unroll
    for (int i = 0; i < 4; ++i) bA[i] = *(const bfrag*)&Bb0[i * 512];
#pragma unroll
    for (int i = 0; i < 4; ++i) aA[i] = *(const bfrag*)&Ab0[i * 512];
  }

  // one tile: CURB/CURA consumed; NXTB/NXTA loaded (unless LAST)
#define TILE_BODY(kt_, CURB, CURA, NXTB, NXTA, LAST)                           \
  {                                                                            \
    const int _slc = ((kt_) & 3) * 16384;                                      \
    const short* _AbC = &LDS[_slc + aofs];                                     \
    _Pragma("unroll")                                                          \
    for (int _i = 0; _i < 4; ++_i)                                             \
      CURA[4 + _i] = *(const bfrag*)&_AbC[2048 + _i * 512];                    \
    if ((kt_) + 3 < NKT) STAGE_A((kt_) + 3);                                   \
    __builtin_amdgcn_sched_barrier(0);                                         \
    __builtin_amdgcn_s_setprio(1);                                             \
    _Pragma("unroll")                                                          \
    for (int _m = 0; _m < 4; ++_m)                                             \
      _Pragma("unroll")                                                        \
      for (int _n = 0; _n < 4; ++_n)                                           \
        acc[_m][_n] = __builtin_amdgcn_mfma_f32_16x16x32_bf16(                 \
            CURB[_n], CURA[_m], acc[_m][_n], 0, 0, 0);                         \
    __builtin_amdgcn_s_setprio(0);                                             \
    if (!(LAST)) {                                                             \
      const int _sln = (((kt_) + 1) & 3) * 16384;                              \
      const short* _AbN = &LDS[_sln + aofs];                                   \
      const short* _BbN = &LDS[_sln + bofs];                                   \
      _Pragma("unroll")                                                        \
      for (int _i = 0; _i < 4; ++_i) NXTB[_i] = *(const bfrag*)&_BbN[_i * 512];\
      _Pragma("unroll")                                                        \
      for (int _i = 0; _i < 4; ++_i) NXTA[_i] = *(const bfrag*)&_AbN[_i * 512];\
    }                                                                          \
    if ((kt_) + 3 < NKT) STAGE_B((kt_) + 3);                                   \
    __builtin_amdgcn_sched_barrier(0);                                         \
    __builtin_amdgcn_s_setprio(1);                                             \
    _Pragma("unroll")                                                          \
    for (int _m = 4; _m < 8; ++_m)                                             \
      _Pragma("unroll")                                                        \
      for (int _n = 0; _n < 4; ++_n)                                           \
        acc[_m][_n] = __builtin_amdgcn_mfma_f32_16x16x32_bf16(                 \
            CURB[_n], CURA[_m], acc[_m][_n], 0, 0, 0);                         \
    __builtin_amdgcn_s_setprio(0);                                             \
    if (!(LAST)) {                                                             \
      if ((kt_) + 4 < NKT) { asm volatile("s_waitcnt vmcnt(4)" ::: "memory"); }\
      else                 { asm volatile("s_waitcnt vmcnt(0)" ::: "memory"); }\
      __builtin_amdgcn_s_barrier();                                            \
      asm volatile("" ::: "memory");                                          \
    }                                                                          \
  }

  for (int kt = 0; kt < NKT; kt += 2) {
    TILE_BODY(kt,     bA, aA, bB, aB, false);
    TILE_BODY(kt + 1, bB, aB, bA, aA, (kt + 2 >= NKT));
  }

  const bool bf = flag[0] != 0;
  float* of = (float*)outp;
  unsigned short* oh = (unsigned short*)outp;
#pragma unroll
  for (int m = 0; m < 8; ++m)
#pragma unroll
    for (int n = 0; n < 4; ++n) {
      int gr = tm + wr * 128 + m * 16 + lr;
      int gc = tn + wc * 64 + n * 16 + kq * 4;
      if (!bf) {
        *(f32x4*)&of[(size_t)gr * D + gc] = acc[m][n];
      } else {
        s16x4 o;
#pragma unroll
        for (int q = 0; q < 4; ++q) o[q] = f2bf(acc[m][n][q]);
        *(s16x4*)&oh[(size_t)gr * D + gc] = o;
      }
    }
#undef STAGE_A
#undef STAGE_B
#undef TILE_BODY
}

// ---------------------------------------------------------------- host
extern "C" void kernel_launch(void* const* d_in, const int* in_sizes, int n_in,
                              void* d_out, int out_size, void* d_ws, size_t ws_size,
                              hipStream_t stream) {
  const void* x  = d_in[0];
  const void* bw = d_in[1];
  const void* rw = d_in[2];
  const void* lA = d_in[3];
  const void* lB = d_in[4];

  char* ws = (char*)d_ws;
  const size_t XB_BYTES  = (size_t)NT * KX * 2;
  const size_t WB_BYTES  = (size_t)D * KX * 2;
  const size_t ABT_BYTES = (size_t)KE * D * 2;
  const size_t WD_BYTES  = (size_t)NT * NE * 4;
  const size_t NEED = 256 + XB_BYTES + WB_BYTES + ABT_BYTES + WD_BYTES;
  if (ws_size < NEED) return;

  int*   flag   = (int*)ws;
  short* Xb     = (short*)(ws + 256);
  short* Wb     = (short*)(ws + 256 + XB_BYTES);
  short* Abt    = (short*)(ws + 256 + XB_BYTES + WB_BYTES);
  float* wdense = (float*)(ws + 256 + XB_BYTES + WB_BYTES + ABT_BYTES);

  hipLaunchKernelGGL(moe_k_detect, dim3(1), dim3(64), 0, stream,
                     (const unsigned*)x, flag);
  hipLaunchKernelGGL(moe_k_prep, dim3(8336), dim3(256), 0, stream,
                     bw, lA, lB, flag, Wb, Abt);
  hipLaunchKernelGGL(moe_k_xrouter, dim3(NT / 4), dim3(256), 0, stream,
                     x, rw, flag, Xb, wdense);
  hipLaunchKernelGGL(moe_k_mid2, dim3(256), dim3(256), 0, stream,
                     Xb, Abt, wdense, Xb);
  hipLaunchKernelGGL(moe_k_main8, dim3(512), dim3(512), 0, stream,
                     Xb, Wb, flag, d_out);
}

// Round 11
// 394.254 us; speedup vs baseline: 1.0212x; 1.0007x over previous
//
#include <hip/hip_runtime.h>
#include <math.h>

#define DI __device__ __forceinline__

typedef __attribute__((ext_vector_type(4))) float  f32x4;
typedef __attribute__((ext_vector_type(4))) short  s16x4;
typedef __attribute__((ext_vector_type(8))) short  s16x8;
typedef __attribute__((ext_vector_type(4))) float  ffrag;
typedef s16x8 bfrag;

constexpr int NT = 8192;   // B*S tokens
constexpr int D  = 4096;
constexpr int NE = 8;      // experts
constexpr int KE = 128;    // E * R
constexpr int KX = D + KE; // 4224 extended K

DI short f2bf(float f) {
  unsigned u = __builtin_bit_cast(unsigned, f);
  u += 0x7FFFu + ((u >> 16) & 1u);   // RNE
  return (short)(u >> 16);
}
DI float bf2f(short h) {
  unsigned u = ((unsigned)(unsigned short)h) << 16;
  return __builtin_bit_cast(float, u);
}

#define GLOAD16(gp, lp)                                                        \
  __builtin_amdgcn_global_load_lds(                                            \
      (const __attribute__((address_space(1))) void*)(gp),                     \
      (__attribute__((address_space(3))) void*)(lp), 16, 0, 0)

// ---------------------------------------------------------------- detect (standalone)
__global__ void moe_k_detect(const unsigned* __restrict__ x, int* __restrict__ flag) {
  int l = threadIdx.x;
  int cnt = 0;
  for (int i = l; i < 2048; i += 64) {
    unsigned e = (x[i] >> 23) & 0xFFu;
    cnt += (e >= 110u && e <= 140u) ? 1 : 0;
  }
#pragma unroll
  for (int o = 32; o; o >>= 1) cnt += __shfl_xor(cnt, o);
  if (l == 0) flag[0] = (cnt > 1024) ? 0 : 1;
}

// ---------------------------------------------------------------- prep + xrouter (R5 fused form — measured-best chain)
__global__ __launch_bounds__(256)
void moe_k_prep_xr(const void* __restrict__ wp, const void* __restrict__ lAp,
                   const void* __restrict__ lBp, const void* __restrict__ xp,
                   const void* __restrict__ rp, const int* __restrict__ flag,
                   short* __restrict__ Wb, short* __restrict__ Abt,
                   short* __restrict__ Xb, float* __restrict__ wdense) {
  const bool bf = flag[0] != 0;
  int b = blockIdx.x, t = threadIdx.x;
  if (b < 8192) {
    int tid = b * 256 + t;
    int row = tid >> 9;
    int col = (tid & 511) << 3;
    s16x8 o;
    if (!bf) {
      const float* Wf = (const float*)wp;
      f32x4 v0 = *(const f32x4*)&Wf[(size_t)row * 4096 + col];
      f32x4 v1 = *(const f32x4*)&Wf[(size_t)row * 4096 + col + 4];
      o[0] = f2bf(v0[0]); o[1] = f2bf(v0[1]); o[2] = f2bf(v0[2]); o[3] = f2bf(v0[3]);
      o[4] = f2bf(v1[0]); o[5] = f2bf(v1[1]); o[6] = f2bf(v1[2]); o[7] = f2bf(v1[3]);
    } else {
      o = *(const s16x8*)&((const short*)wp)[(size_t)row * 4096 + col];
    }
    *(s16x8*)&Wb[(size_t)row * KX + col] = o;
  } else if (b < 8208) {
    int d = (b - 8192) * 256 + t;
    for (int j0 = 0; j0 < KE; j0 += 8) {
      s16x8 o;
#pragma unroll
      for (int i = 0; i < 8; ++i) {
        float v = bf ? bf2f(((const short*)lBp)[(size_t)(j0 + i) * 4096 + d])
                     : ((const float*)lBp)[(size_t)(j0 + i) * 4096 + d];
        o[i] = f2bf(2.0f * v);
      }
      *(s16x8*)&Wb[(size_t)d * KX + 4096 + j0] = o;
    }
  } else if (b < 8336) {
    int j = b - 8208;
    int e = j >> 4, r = j & 15;
    for (int d = t; d < 4096; d += 256) {
      size_t src = ((size_t)e * 4096 + d) * 16 + r;
      short v = bf ? ((const short*)lAp)[src] : f2bf(((const float*)lAp)[src]);
      Abt[(size_t)j * 4096 + d] = v;
    }
  } else {
    int wv = t >> 6, l = t & 63;
    int n = (b - 8336) * 4 + wv;
    float acc[NE];
#pragma unroll
    for (int e = 0; e < NE; ++e) acc[e] = 0.f;
    const float* xf = (const float*)xp;
    const short* xh = (const short*)xp;
    const float* rf = (const float*)rp;
    const short* rh = (const short*)rp;
    for (int it = 0; it < 16; ++it) {
      int d = it * 256 + l * 4;
      float x0, x1, x2, x3;
      s16x4 xo;
      if (!bf) {
        f32x4 v = *(const f32x4*)&xf[(size_t)n * D + d];
        x0 = v[0]; x1 = v[1]; x2 = v[2]; x3 = v[3];
        xo[0] = f2bf(x0); xo[1] = f2bf(x1); xo[2] = f2bf(x2); xo[3] = f2bf(x3);
      } else {
        xo = *(const s16x4*)&xh[(size_t)n * D + d];
        x0 = bf2f(xo[0]); x1 = bf2f(xo[1]); x2 = bf2f(xo[2]); x3 = bf2f(xo[3]);
      }
      *(s16x4*)&Xb[(size_t)n * KX + d] = xo;
#pragma unroll
      for (int e = 0; e < NE; ++e) {
        if (!bf) {
          f32x4 w = *(const f32x4*)&rf[(size_t)e * D + d];
          acc[e] += x0 * w[0] + x1 * w[1] + x2 * w[2] + x3 * w[3];
        } else {
          s16x4 w = *(const s16x4*)&rh[(size_t)e * D + d];
          acc[e] += x0 * bf2f(w[0]) + x1 * bf2f(w[1]) + x2 * bf2f(w[2]) + x3 * bf2f(w[3]);
        }
      }
    }
#pragma unroll
    for (int e = 0; e < NE; ++e) {
#pragma unroll
      for (int o = 32; o; o >>= 1) acc[e] += __shfl_xor(acc[e], o);
    }
    float m = acc[0];
#pragma unroll
    for (int e = 1; e < NE; ++e) m = fmaxf(m, acc[e]);
    float p[NE];
#pragma unroll
    for (int e = 0; e < NE; ++e) p[e] = __expf(acc[e] - m);
    int i1 = 0; float v1 = p[0];
#pragma unroll
    for (int e = 1; e < NE; ++e) { if (p[e] > v1) { v1 = p[e]; i1 = e; } }
    int i2 = 0; float v2 = -1.f;
#pragma unroll
    for (int e = 0; e < NE; ++e) { if (e != i1 && p[e] > v2) { v2 = p[e]; i2 = e; } }
    float inv = 1.f / (v1 + v2);
    if (l < NE) {
      float w = (l == i1) ? v1 * inv : ((l == i2) ? v2 * inv : 0.f);
      wdense[(size_t)n * NE + l] = w;
    }
  }
}

// ---------------------------------------------------------------- mid GEMM v2 (R5 verbatim)
__global__ __launch_bounds__(256)
void moe_k_mid2(const short* __restrict__ Xb, const short* __restrict__ Abt,
                const float* __restrict__ wdense, short* __restrict__ XbW) {
  __shared__ __align__(16) short LDS[16384];
  const int t = threadIdx.x, l = t & 63, wv = t >> 6;
  const int wr = wv >> 1, wc = wv & 1;
  const int lr = l & 15, kq = l >> 4;
  const int m0 = (blockIdx.x >> 1) * 64;
  const int j0 = (blockIdx.x & 1) * 64;

  ffrag acc[2][2];
#pragma unroll
  for (int i = 0; i < 2; ++i)
#pragma unroll
    for (int j = 0; j < 2; ++j)
#pragma unroll
      for (int q = 0; q < 4; ++q) acc[i][j][q] = 0.f;

  const int srow = t >> 2, sslot = t & 3;
#define MSTAGE(kt_)                                                            \
  do {                                                                         \
    int _k0 = (kt_) * 32, _b = ((kt_) & 3) * 4096;                             \
    GLOAD16(&Xb[(size_t)(m0 + srow) * KX + _k0 + sslot * 8], &LDS[_b + t * 8]);\
    GLOAD16(&Abt[(size_t)(j0 + srow) * 4096 + _k0 + sslot * 8],                \
            &LDS[_b + 2048 + t * 8]);                                          \
  } while (0)

  MSTAGE(0); MSTAGE(1); MSTAGE(2);
  constexpr int NKT = 128;

  for (int kt = 0; kt < NKT; ++kt) {
    if (kt + 2 < NKT)      asm volatile("s_waitcnt vmcnt(4)" ::: "memory");
    else if (kt + 1 < NKT) asm volatile("s_waitcnt vmcnt(2)" ::: "memory");
    else                   asm volatile("s_waitcnt vmcnt(0)" ::: "memory");
    __builtin_amdgcn_s_barrier();
    __builtin_amdgcn_sched_barrier(0);

    const int bufs = (kt & 3) * 4096;
    const short* As = &LDS[bufs + (wr * 32 + lr) * 32 + kq * 8];
    const short* Bs = &LDS[bufs + 2048 + (wc * 32 + lr) * 32 + kq * 8];
    bfrag a0 = *(const bfrag*)&As[0];
    bfrag a1 = *(const bfrag*)&As[512];
    bfrag b0 = *(const bfrag*)&Bs[0];
    bfrag b1 = *(const bfrag*)&Bs[512];
    if (kt + 3 < NKT) MSTAGE(kt + 3);
    asm volatile("" ::: "memory");
    acc[0][0] = __builtin_amdgcn_mfma_f32_16x16x32_bf16(b0, a0, acc[0][0], 0, 0, 0);
    acc[0][1] = __builtin_amdgcn_mfma_f32_16x16x32_bf16(b1, a0, acc[0][1], 0, 0, 0);
    acc[1][0] = __builtin_amdgcn_mfma_f32_16x16x32_bf16(b0, a1, acc[1][0], 0, 0, 0);
    acc[1][1] = __builtin_amdgcn_mfma_f32_16x16x32_bf16(b1, a1, acc[1][1], 0, 0, 0);
  }

#pragma unroll
  for (int m = 0; m < 2; ++m)
#pragma unroll
    for (int n = 0; n < 2; ++n) {
      int gr = m0 + wr * 32 + m * 16 + lr;
      int jb = j0 + wc * 32 + n * 16 + kq * 4;
      int e  = jb >> 4;
      float w = wdense[(size_t)gr * NE + e];
      s16x4 o;
#pragma unroll
      for (int q = 0; q < 4; ++q) o[q] = f2bf(acc[m][n][q] * w);
      *(s16x4*)&XbW[(size_t)gr * KX + 4096 + jb] = o;
    }
#undef MSTAGE
}

// ---------------------------------------------------------------- main GEMM v6 — faithful m201 geometry
// 256x256 tile, BK=64 (NKT=66), 8 waves (2Mx4N, wave-tile 128x64).
// LDS 128KB = 2 dbuf x (A 32KB + B 32KB); each 32KB region = 2 ks-subregions
// of [256 rows][4 slots x 16B] with the R3-proven involution slot^((row>>1)&3)
// (coalesced global 64B rows, 0 bank conflicts measured).
// 8 staging units/tile (A/B x half x ks), 1 gload/thread/unit.
// 4 phases/tile x 16 MFMA, 2 barriers/phase (m201), counted vmcnt(4) at end
// of ph2 (gates this tile's ks1 reads) and ph4 (gates next tile's ks0 reads).
__global__ __launch_bounds__(512, 2)
void moe_k_main9(const short* __restrict__ Xb, const short* __restrict__ Wb,
                 const int* __restrict__ flag, void* __restrict__ outp) {
  __shared__ __align__(16) short LDS[65536];  // 128 KiB
  const int t = threadIdx.x;
  const int l = t & 63;
  const int wv = t >> 6;
  const int wr = wv >> 2;        // 0..1
  const int wc = wv & 3;         // 0..3
  const int lr = l & 15;
  const int kq = l >> 4;         // 0..3

  int wg = blockIdx.x;
  int swz = (wg & 7) * 64 + (wg >> 3);
  const int tm = (swz >> 4) * 256;
  const int tn = (swz & 15) * 256;

  ffrag acc[8][4];
#pragma unroll
  for (int i = 0; i < 8; ++i)
#pragma unroll
    for (int j = 0; j < 4; ++j)
#pragma unroll
      for (int q = 0; q < 4; ++q) acc[i][j][q] = 0.f;

  constexpr int NKT = KX / 64;  // 66

  // stage one unit: (tile kt, region REG: 0=A,16384=B, half h, ksub ks)
  // thread t -> row-in-half rp = t>>2, slot = t&3, global kc = slot^((rp>>1)&3)
#define SU(kt_, REG_, src_, tb_, h_, ks_)                                      \
  do {                                                                         \
    int _rp = t >> 2;                                                          \
    int _kc = (t & 3) ^ ((_rp >> 1) & 3);                                      \
    GLOAD16(&src_[(size_t)((tb_) + (h_) * 128 + _rp) * KX +                    \
                  (kt_) * 64 + (ks_) * 32 + _kc * 8],                          \
            &LDS[((kt_) & 1) * 32768 + (REG_) + (ks_) * 8192 +                 \
                 (h_) * 4096 + t * 8]);                                        \
  } while (0)
#define SU_A(kt_, h_, ks_) SU(kt_, 0,     Xb, tm, h_, ks_)
#define SU_B(kt_, h_, ks_) SU(kt_, 16384, Wb, tn, h_, ks_)

  // prologue: tile0 all 8 units, tile1 ks0 units (12 loads/thread)
  SU_A(0, 0, 0); SU_A(0, 1, 0); SU_B(0, 0, 0); SU_B(0, 1, 0);
  SU_A(0, 0, 1); SU_A(0, 1, 1); SU_B(0, 0, 1); SU_B(0, 1, 1);
  SU_A(1, 0, 0); SU_A(1, 1, 0); SU_B(1, 0, 0); SU_B(1, 1, 0);
  asm volatile("s_waitcnt vmcnt(8)" ::: "memory");
  __builtin_amdgcn_s_barrier();
  asm volatile("" ::: "memory");

  // per-lane fragment bases (shorts)
  const int kx = kq ^ ((lr >> 1) & 3);
  const int abase = (wr * 128 + lr) * 32 + kx * 8;
  const int bbase = 16384 + (wc * 64 + lr) * 32 + kx * 8;

#define MM(m_, n_, bv_, av_)                                                   \
  acc[m_][n_] = __builtin_amdgcn_mfma_f32_16x16x32_bf16(bv_, av_, acc[m_][n_], 0, 0, 0);

#define PH_TOP()                                                               \
  __builtin_amdgcn_s_barrier();                                                \
  asm volatile("s_waitcnt lgkmcnt(0)" ::: "memory");                           \
  __builtin_amdgcn_sched_barrier(0);                                           \
  __builtin_amdgcn_s_setprio(1);
#define PH_END()                                                               \
  __builtin_amdgcn_s_setprio(0);                                               \
  __builtin_amdgcn_s_barrier();                                                \
  asm volatile("" ::: "memory");

  for (int kt = 0; kt < NKT; ++kt) {
    const int bufS = (kt & 1) * 32768;
    const short* Ap = &LDS[bufS + abase];           // ks0
    const short* Bp = &LDS[bufS + bbase];
    const bool more = (kt + 1 < NKT);

    // ---- ph1: ks0, m0-3 (8 reads, 16 MFMA)
    bfrag b0 = *(const bfrag*)&Bp[0];
    bfrag b1 = *(const bfrag*)&Bp[512];
    bfrag b2 = *(const bfrag*)&Bp[1024];
    bfrag b3 = *(const bfrag*)&Bp[1536];
    bfrag a0 = *(const bfrag*)&Ap[0];
    bfrag a1 = *(const bfrag*)&Ap[512];
    bfrag a2 = *(const bfrag*)&Ap[1024];
    bfrag a3 = *(const bfrag*)&Ap[1536];
    if (more && kt > 0) { SU_A(kt + 1, 0, 0); SU_A(kt + 1, 1, 0); }
    PH_TOP()
    MM(0, 0, b0, a0) MM(0, 1, b1, a0) MM(0, 2, b2, a0) MM(0, 3, b3, a0)
    MM(1, 0, b0, a1) MM(1, 1, b1, a1) MM(1, 2, b2, a1) MM(1, 3, b3, a1)
    MM(2, 0, b0, a2) MM(2, 1, b1, a2) MM(2, 2, b2, a2) MM(2, 3, b3, a2)
    MM(3, 0, b0, a3) MM(3, 1, b1, a3) MM(3, 2, b2, a3) MM(3, 3, b3, a3)
    PH_END()

    // ---- ph2: ks0, m4-7 (4 reads, 16 MFMA) + vmcnt gate for this tile's ks1
    bfrag a4 = *(const bfrag*)&Ap[2048];
    bfrag a5 = *(const bfrag*)&Ap[2560];
    bfrag a6 = *(const bfrag*)&Ap[3072];
    bfrag a7 = *(const bfrag*)&Ap[3584];
    if (more && kt > 0) { SU_B(kt + 1, 0, 0); SU_B(kt + 1, 1, 0); }
    if (more) asm volatile("s_waitcnt vmcnt(4)" ::: "memory");
    else      asm volatile("s_waitcnt vmcnt(0)" ::: "memory");
    PH_TOP()
    MM(4, 0, b0, a4) MM(4, 1, b1, a4) MM(4, 2, b2, a4) MM(4, 3, b3, a4)
    MM(5, 0, b0, a5) MM(5, 1, b1, a5) MM(5, 2, b2, a5) MM(5, 3, b3, a5)
    MM(6, 0, b0, a6) MM(6, 1, b1, a6) MM(6, 2, b2, a6) MM(6, 3, b3, a6)
    MM(7, 0, b0, a7) MM(7, 1, b1, a7) MM(7, 2, b2, a7) MM(7, 3, b3, a7)
    PH_END()

    // ---- ph3: ks1, m4-7 (8 reads, 16 MFMA)
    const short* Aq = Ap + 8192;   // ks1 region
    const short* Bq = Bp + 8192;
    bfrag c0 = *(const bfrag*)&Bq[0];
    bfrag c1 = *(const bfrag*)&Bq[512];
    bfrag c2 = *(const bfrag*)&Bq[1024];
    bfrag c3 = *(const bfrag*)&Bq[1536];
    bfrag e4 = *(const bfrag*)&Aq[2048];
    bfrag e5 = *(const bfrag*)&Aq[2560];
    bfrag e6 = *(const bfrag*)&Aq[3072];
    bfrag e7 = *(const bfrag*)&Aq[3584];
    if (more) { SU_A(kt + 1, 0, 1); SU_A(kt + 1, 1, 1); }
    PH_TOP()
    MM(4, 0, c0, e4) MM(4, 1, c1, e4) MM(4, 2, c2, e4) MM(4, 3, c3, e4)
    MM(5, 0, c0, e5) MM(5, 1, c1, e5) MM(5, 2, c2, e5) MM(5, 3, c3, e5)
    MM(6, 0, c0, e6) MM(6, 1, c1, e6) MM(6, 2, c2, e6) MM(6, 3, c3, e6)
    MM(7, 0, c0, e7) MM(7, 1, c1, e7) MM(7, 2, c2, e7) MM(7, 3, c3, e7)
    PH_END()

    // ---- ph4: ks1, m0-3 (4 reads, 16 MFMA) + vmcnt gate for next tile's ks0
    bfrag e0 = *(const bfrag*)&Aq[0];
    bfrag e1 = *(const bfrag*)&Aq[512];
    bfrag e2 = *(const bfrag*)&Aq[1024];
    bfrag e3 = *(const bfrag*)&Aq[1536];
    if (more) { SU_B(kt + 1, 0, 1); SU_B(kt + 1, 1, 1); }
    if (more) asm volatile("s_waitcnt vmcnt(4)" ::: "memory");
    PH_TOP()
    MM(0, 0, c0, e0) MM(0, 1, c1, e0) MM(0, 2, c2, e0) MM(0, 3, c3, e0)
    MM(1, 0, c0, e1) MM(1, 1, c1, e1) MM(1, 2, c2, e1) MM(1, 3, c3, e1)
    MM(2, 0, c0, e2) MM(2, 1, c1, e2) MM(2, 2, c2, e2) MM(2, 3, c3, e2)
    MM(3, 0, c0, e3) MM(3, 1, c1, e3) MM(3, 2, c2, e3) MM(3, 3, c3, e3)
    PH_END()
  }

  const bool bf = flag[0] != 0;
  float* of = (float*)outp;
  unsigned short* oh = (unsigned short*)outp;
#pragma unroll
  for (int m = 0; m < 8; ++m)
#pragma unroll
    for (int n = 0; n < 4; ++n) {
      int gr = tm + wr * 128 + m * 16 + lr;
      int gc = tn + wc * 64 + n * 16 + kq * 4;
      if (!bf) {
        *(f32x4*)&of[(size_t)gr * D + gc] = acc[m][n];
      } else {
        s16x4 o;
#pragma unroll
        for (int q = 0; q < 4; ++q) o[q] = f2bf(acc[m][n][q]);
        *(s16x4*)&oh[(size_t)gr * D + gc] = o;
      }
    }
#undef SU
#undef SU_A
#undef SU_B
#undef MM
#undef PH_TOP
#undef PH_END
}

// ---------------------------------------------------------------- host
extern "C" void kernel_launch(void* const* d_in, const int* in_sizes, int n_in,
                              void* d_out, int out_size, void* d_ws, size_t ws_size,
                              hipStream_t stream) {
  const void* x  = d_in[0];
  const void* bw = d_in[1];
  const void* rw = d_in[2];
  const void* lA = d_in[3];
  const void* lB = d_in[4];

  char* ws = (char*)d_ws;
  const size_t XB_BYTES  = (size_t)NT * KX * 2;
  const size_t WB_BYTES  = (size_t)D * KX * 2;
  const size_t ABT_BYTES = (size_t)KE * D * 2;
  const size_t WD_BYTES  = (size_t)NT * NE * 4;
  const size_t NEED = 256 + XB_BYTES + WB_BYTES + ABT_BYTES + WD_BYTES;
  if (ws_size < NEED) return;

  int*   flag   = (int*)ws;
  short* Xb     = (short*)(ws + 256);
  short* Wb     = (short*)(ws + 256 + XB_BYTES);
  short* Abt    = (short*)(ws + 256 + XB_BYTES + WB_BYTES);
  float* wdense = (float*)(ws + 256 + XB_BYTES + WB_BYTES + ABT_BYTES);

  hipLaunchKernelGGL(moe_k_detect, dim3(1), dim3(64), 0, stream,
                     (const unsigned*)x, flag);
  hipLaunchKernelGGL(moe_k_prep_xr, dim3(10384), dim3(256), 0, stream,
                     bw, lA, lB, x, rw, flag, Wb, Abt, Xb, wdense);
  hipLaunchKernelGGL(moe_k_mid2, dim3(256), dim3(256), 0, stream,
                     Xb, Abt, wdense, Xb);
  hipLaunchKernelGGL(moe_k_main9, dim3(512), dim3(512), 0, stream,
                     Xb, Wb, flag, d_out);
}